// Round 7
// baseline (586.374 us; speedup 1.0000x reference)
//
#include <hip/hip_runtime.h>
#include <hip/hip_bf16.h>
#include <math.h>

#define NUM_USERS 60000
#define NUM_ITEMS 30000
#define DD 64
#define SEMD 1024
#define HIDD 32
#define KNBR 32
#define NNZE 2000000
#define NLAYERS 3
#define BBATCH 4096
#define LALPHA 0.2f
#define NTOT (NUM_USERS + NUM_ITEMS)
#define SCAN_NB ((NTOT + 1023) / 1024)  // 88
#define NBKT 704                         // buckets = row>>7
#define BCAP 3328                        // bucket LDS cap

typedef unsigned short ushort_t;
typedef short s16x8 __attribute__((ext_vector_type(8)));
typedef float f32x4 __attribute__((ext_vector_type(4)));

__device__ __forceinline__ ushort_t f2bf(float x) {  // RNE
    unsigned u = __float_as_uint(x);
    return (ushort_t)((u + 0x7FFFu + ((u >> 16) & 1u)) >> 16);
}
__device__ __forceinline__ float bf2f(ushort_t s) {
    return __uint_as_float(((unsigned)s) << 16);
}

// truncation split of 8 floats into bf16 hi/lo fragments
__device__ __forceinline__ void split8(const float4& f0, const float4& f1,
                                       s16x8& hi, s16x8& lo) {
    float f[8] = {f0.x, f0.y, f0.z, f0.w, f1.x, f1.y, f1.z, f1.w};
#pragma unroll
    for (int j = 0; j < 8; ++j) {
        unsigned u = __float_as_uint(f[j]);
        hi[j] = (short)(u >> 16);
        lo[j] = (short)(__float_as_uint(f[j] - __uint_as_float(u & 0xFFFF0000u)) >> 16);
    }
}

// ---------- W split (transposed bf16 hi/lo) + fused wa1/wa2 ----------
__global__ __launch_bounds__(256) void wsplit(const float* __restrict__ Wu,
                                              const float* __restrict__ Ws,
                                              ushort_t* __restrict__ hiU, ushort_t* __restrict__ loU,
                                              ushort_t* __restrict__ hiS, ushort_t* __restrict__ loS,
                                              const float* __restrict__ W_att,
                                              const float* __restrict__ a_att,
                                              float* __restrict__ wa1,
                                              float* __restrict__ wa2) {
    if (blockIdx.x == 512) {  // fused prep_wa
        int t = threadIdx.x;
#pragma unroll
        for (int r = 0; r < 4; ++r) {
            int k = t * 4 + r;
            float d1 = 0.f, d2 = 0.f;
#pragma unroll
            for (int h = 0; h < HIDD; ++h) {
                float w = W_att[k * HIDD + h];
                d1 += w * a_att[h];
                d2 += w * a_att[HIDD + h];
            }
            wa1[k] = d1;
            wa2[k] = d2;
        }
        return;
    }
    int id = blockIdx.x * 256 + threadIdx.x;  // 0..131071
    int i = id & 65535;
    int k = i & 1023;
    int c = i >> 10;
    float x = (id < 65536) ? Wu[(size_t)k * DD + c] : Ws[(size_t)k * DD + c];
    ushort_t h = f2bf(x);
    ushort_t l = f2bf(x - bf2f(h));
    ushort_t* dh = (id < 65536) ? hiU : hiS;
    ushort_t* dl = (id < 65536) ? loU : loS;
    dh[(size_t)c * SEMD + k] = h;
    dl[(size_t)c * SEMD + k] = l;
}

// ---------- LDS-free MFMA bf16x3 GEMM + bias + ELU + merge (+ fused s1/s2) ----------
// A:[M,1024] fp32 streamed straight into fragments; WT hi/lo:[64][1024] bf16 (L2-hot).
// 256 threads = 4 waves; wave w owns rows [blk*128 + w*32, +32) x all 64 cols.
template <bool DOS12>
__global__ __launch_bounds__(256) void gemm_mfma(
    const float* __restrict__ A,
    const ushort_t* __restrict__ WThi,
    const ushort_t* __restrict__ WTlo,
    const float* __restrict__ bias,
    const float* __restrict__ emb,
    float* __restrict__ out32,
    ushort_t* __restrict__ out16,
    int M,
    const float* __restrict__ wa1,
    const float* __restrict__ wa2,
    float* __restrict__ s1,
    float* __restrict__ s2) {
    const int tid = threadIdx.x;
    const int lane = tid & 63;
    const int w = tid >> 6;
    const int l15 = lane & 15;
    const int l4 = lane >> 4;
    const int rbase = blockIdx.x * 128 + w * 32;

    // A row pointers (clamped; garbage rows never stored)
    const float* ap[2];
#pragma unroll
    for (int rg = 0; rg < 2; ++rg) {
        int r = rbase + rg * 16 + l15;
        ap[rg] = A + (size_t)min(r, M - 1) * SEMD + l4 * 8;
    }
    // W fragment pointers
    const ushort_t* wph[4];
    const ushort_t* wpl[4];
#pragma unroll
    for (int cg = 0; cg < 4; ++cg) {
        int off = (cg * 16 + l15) * SEMD + l4 * 8;
        wph[cg] = WThi + off;
        wpl[cg] = WTlo + off;
    }

    f32x4 acc[2][4] = {};
    float s1p[2] = {}, s2p[2] = {};

#pragma unroll 2
    for (int k0 = 0; k0 < SEMD; k0 += 32) {
        s16x8 bh[4], bl[4];
#pragma unroll
        for (int cg = 0; cg < 4; ++cg) {
            bh[cg] = *(const s16x8*)(wph[cg] + k0);
            bl[cg] = *(const s16x8*)(wpl[cg] + k0);
        }
        float4 a0[2], a1[2];
#pragma unroll
        for (int rg = 0; rg < 2; ++rg) {
            a0[rg] = *(const float4*)(ap[rg] + k0);
            a1[rg] = *(const float4*)(ap[rg] + k0 + 4);
        }
        if (DOS12) {
            float4 v1a = *(const float4*)(wa1 + k0 + l4 * 8);
            float4 v1b = *(const float4*)(wa1 + k0 + l4 * 8 + 4);
            float4 v2a = *(const float4*)(wa2 + k0 + l4 * 8);
            float4 v2b = *(const float4*)(wa2 + k0 + l4 * 8 + 4);
#pragma unroll
            for (int rg = 0; rg < 2; ++rg) {
                s1p[rg] += a0[rg].x * v1a.x + a0[rg].y * v1a.y + a0[rg].z * v1a.z + a0[rg].w * v1a.w
                         + a1[rg].x * v1b.x + a1[rg].y * v1b.y + a1[rg].z * v1b.z + a1[rg].w * v1b.w;
                s2p[rg] += a0[rg].x * v2a.x + a0[rg].y * v2a.y + a0[rg].z * v2a.z + a0[rg].w * v2a.w
                         + a1[rg].x * v2b.x + a1[rg].y * v2b.y + a1[rg].z * v2b.z + a1[rg].w * v2b.w;
            }
        }
        s16x8 ah[2], al[2];
#pragma unroll
        for (int rg = 0; rg < 2; ++rg) split8(a0[rg], a1[rg], ah[rg], al[rg]);
#pragma unroll
        for (int rg = 0; rg < 2; ++rg)
#pragma unroll
            for (int cg = 0; cg < 4; ++cg) {
                acc[rg][cg] = __builtin_amdgcn_mfma_f32_16x16x32_bf16(ah[rg], bh[cg], acc[rg][cg], 0, 0, 0);
                acc[rg][cg] = __builtin_amdgcn_mfma_f32_16x16x32_bf16(ah[rg], bl[cg], acc[rg][cg], 0, 0, 0);
                acc[rg][cg] = __builtin_amdgcn_mfma_f32_16x16x32_bf16(al[rg], bh[cg], acc[rg][cg], 0, 0, 0);
            }
    }

    if (DOS12) {
#pragma unroll
        for (int rg = 0; rg < 2; ++rg) {
            float v1 = s1p[rg], v2 = s2p[rg];
            v1 += __shfl_xor(v1, 16); v1 += __shfl_xor(v1, 32);
            v2 += __shfl_xor(v2, 16); v2 += __shfl_xor(v2, 32);
            int r = rbase + rg * 16 + l15;
            if (l4 == 0 && r < M) {
                s1[r] = v1;
                s2[r] = v2;
            }
        }
    }

    // epilogue: D col = cg*16 + l15, row-in-16 = l4*4 + j
#pragma unroll
    for (int rg = 0; rg < 2; ++rg)
#pragma unroll
        for (int cg = 0; cg < 4; ++cg) {
            int col = cg * 16 + l15;
            float b = bias[col];
#pragma unroll
            for (int j = 0; j < 4; ++j) {
                int grow = rbase + rg * 16 + l4 * 4 + j;
                if (grow < M) {
                    float x = acc[rg][cg][j] + b;
                    float e = x > 0.f ? x : (expf(x) - 1.f);
                    float v = (emb[(size_t)grow * DD + col] + e) * 0.5f;
                    out32[(size_t)grow * DD + col] = v;
                    out16[(size_t)grow * DD + col] = f2bf(v);
                }
            }
        }
}

// ---------- attention + h' + merge: one wave per item row ----------
__global__ __launch_bounds__(256) void att_kernel(const int* __restrict__ adj,
                                                  const float* __restrict__ s1,
                                                  const float* __restrict__ s2,
                                                  const float* __restrict__ M0,
                                                  const ushort_t* __restrict__ M0h,
                                                  ushort_t* __restrict__ cur16,
                                                  float* __restrict__ sum_) {
    int gid = blockIdx.x * 256 + threadIdx.x;
    int row = gid >> 6;
    int lane = gid & 63;
    if (row >= NUM_ITEMS) return;
    int kk = lane & 31;
    int col = adj[(size_t)row * KNBR + kk];
    float e = s1[col] + s2[row];
    e = e > 0.f ? e : LALPHA * e;
    float mx = e;
#pragma unroll
    for (int m = 1; m < 32; m <<= 1) mx = fmaxf(mx, __shfl_xor(mx, m));
    float ex = expf(e - mx);
    float ssum = ex;
#pragma unroll
    for (int m = 1; m < 32; m <<= 1) ssum += __shfl_xor(ssum, m);
    float wgt = ex / ssum;
    float h = 0.f;
#pragma unroll
    for (int k = 0; k < 32; ++k) {
        int ck = __builtin_amdgcn_readlane(col, k);
        float wk = __uint_as_float((unsigned)__builtin_amdgcn_readlane(
            (int)__float_as_uint(wgt), k));
        h += wk * bf2f(M0h[(size_t)ck * DD + lane]);
    }
    float eh = h > 0.f ? h : (expf(h) - 1.f);
    float v = (M0[(size_t)row * DD + lane] + eh) * 0.5f;
    size_t o = (size_t)(NUM_USERS + row) * DD + lane;
    cur16[o] = f2bf(v);
    sum_[o] = v;
}

// ---------- CSR build ----------
__global__ __launch_bounds__(256) void hist_kernel(const int* __restrict__ rows,
                                                   int* __restrict__ cnt) {
    int e = blockIdx.x * 256 + threadIdx.x;
    if (e < NNZE) atomicAdd(&cnt[rows[e]], 1);
}

__global__ __launch_bounds__(256) void scan_blocksums(const int* __restrict__ cnt,
                                                      int* __restrict__ bsum) {
    __shared__ int ws[4];
    int tid = threadIdx.x;
    int base = blockIdx.x * 1024 + tid * 4;
    int s = 0;
    if (base + 3 < NTOT) {
        int4 v = *(const int4*)(cnt + base);
        s = v.x + v.y + v.z + v.w;
    } else {
        for (int i = 0; i < 4; ++i)
            if (base + i < NTOT) s += cnt[base + i];
    }
#pragma unroll
    for (int m = 32; m; m >>= 1) s += __shfl_xor(s, m);
    if ((tid & 63) == 0) ws[tid >> 6] = s;
    __syncthreads();
    if (tid == 0) bsum[blockIdx.x] = ws[0] + ws[1] + ws[2] + ws[3];
}

__global__ __launch_bounds__(128) void scan_bsums(const int* __restrict__ bsum,
                                                  int* __restrict__ boff,
                                                  int* __restrict__ rowptr) {
    __shared__ int sh[128];
    int t = threadIdx.x;
    int v = (t < SCAN_NB) ? bsum[t] : 0;
    sh[t] = v;
    __syncthreads();
    for (int off = 1; off < 128; off <<= 1) {
        int x = (t >= off) ? sh[t - off] : 0;
        __syncthreads();
        sh[t] += x;
        __syncthreads();
    }
    if (t < SCAN_NB) boff[t] = (t == 0) ? 0 : sh[t - 1];
    if (t == 127) rowptr[NTOT] = sh[SCAN_NB - 1];
}

__global__ __launch_bounds__(256) void scan_write(const int* __restrict__ cnt,
                                                  const int* __restrict__ boff,
                                                  int* __restrict__ rowptr,
                                                  int* __restrict__ cursor,
                                                  int* __restrict__ bcursor) {
    __shared__ int wsum[4];
    int tid = threadIdx.x;
    int lane = tid & 63;
    int wave = tid >> 6;
    int base = blockIdx.x * 1024 + tid * 4;

    int e0 = 0, e1 = 0, e2 = 0, e3 = 0;
    if (base + 3 < NTOT) {
        int4 v = *(const int4*)(cnt + base);
        e0 = v.x; e1 = v.y; e2 = v.z; e3 = v.w;
    } else {
        if (base + 0 < NTOT) e0 = cnt[base + 0];
        if (base + 1 < NTOT) e1 = cnt[base + 1];
        if (base + 2 < NTOT) e2 = cnt[base + 2];
    }
    int tsum = e0 + e1 + e2 + e3;

    int s = tsum;
#pragma unroll
    for (int off = 1; off < 64; off <<= 1) {
        int x = __shfl_up(s, off);
        if (lane >= off) s += x;
    }
    if (lane == 63) wsum[wave] = s;
    __syncthreads();
    int woff = 0;
    for (int ww = 0; ww < 4; ++ww)
        if (ww < wave) woff += wsum[ww];
    __syncthreads();
    int excl = boff[blockIdx.x] + woff + (s - tsum);

    int4 r;
    r.x = excl;
    r.y = excl + e0;
    r.z = excl + e0 + e1;
    r.w = excl + e0 + e1 + e2;
    if (base + 3 < NTOT) {
        *(int4*)(rowptr + base) = r;
        *(int4*)(cursor + base) = r;
    } else {
        if (base + 0 < NTOT) { rowptr[base + 0] = r.x; cursor[base + 0] = r.x; }
        if (base + 1 < NTOT) { rowptr[base + 1] = r.y; cursor[base + 1] = r.y; }
        if (base + 2 < NTOT) { rowptr[base + 2] = r.z; cursor[base + 2] = r.z; }
    }
    if ((base & 127) == 0 && base < NTOT) bcursor[base >> 7] = r.x;
}

// ---------- Phase A: bin edges by row>>7, grouped writes ----------
__global__ __launch_bounds__(256) void binA(const int* __restrict__ grows,
                                            const int* __restrict__ gcols,
                                            const float* __restrict__ gvals,
                                            int* __restrict__ bcursor,
                                            int2* __restrict__ temp) {
    __shared__ int hist[NBKT];
    __shared__ int gcur[NBKT];
    int tid = threadIdx.x;
    int base = blockIdx.x * 4096;
    for (int i = tid; i < NBKT; i += 256) hist[i] = 0;
    __syncthreads();
#pragma unroll 4
    for (int j = 0; j < 16; ++j) {
        int e = base + j * 256 + tid;
        if (e < NNZE) atomicAdd(&hist[grows[e] >> 7], 1);
    }
    __syncthreads();
    for (int b = tid; b < NBKT; b += 256) {
        int n = hist[b];
        gcur[b] = n ? atomicAdd(&bcursor[b], n) : 0;
    }
    __syncthreads();
#pragma unroll 4
    for (int j = 0; j < 16; ++j) {
        int e = base + j * 256 + tid;
        if (e < NNZE) {
            int r = grows[e];
            int b = r >> 7;
            int pos = atomicAdd(&gcur[b], 1);
            temp[pos] = make_int2((gcols[e] & 0x1FFFF) | ((r & 127) << 17),
                                  __float_as_int(gvals[e]));
        }
    }
}

// ---------- Phase B: in-place within-bucket re-sort to CSR order ----------
__global__ __launch_bounds__(256) void binB(const int* __restrict__ rowptr,
                                            int* __restrict__ cursor,
                                            int2* __restrict__ sedge) {
    __shared__ int2 ebuf[BCAP];
    int b = blockIdx.x;
    int start = rowptr[b << 7];
    int end = rowptr[min((b + 1) << 7, NTOT)];
    int n = min(end - start, BCAP);
    for (int i = threadIdx.x; i < n; i += 256) ebuf[i] = sedge[start + i];
    __syncthreads();
    for (int i = threadIdx.x; i < n; i += 256) {
        int2 w = ebuf[i];
        int r = (b << 7) + ((w.x >> 17) & 127);
        int pos = atomicAdd(&cursor[r], 1);
        sedge[pos] = make_int2(w.x & 0x1FFFF, w.y);
    }
}

// ---------- SpMM layer (pull, scalar edge loads): one wave per row ----------
__global__ __launch_bounds__(256) void spmm16(const int* __restrict__ rowptr,
                                              const int2* __restrict__ sedge,
                                              const ushort_t* __restrict__ cur,
                                              ushort_t* __restrict__ nxt,
                                              float* __restrict__ sum_) {
    int row = __builtin_amdgcn_readfirstlane((blockIdx.x * 256 + threadIdx.x) >> 6);
    int lane = threadIdx.x & 63;
    if (row >= NTOT) return;
    int i = rowptr[row];
    int e = rowptr[row + 1];
    float acc = 0.f;
    for (; i + 4 <= e; i += 4) {
        int2 ed0 = sedge[i];
        int2 ed1 = sedge[i + 1];
        int2 ed2 = sedge[i + 2];
        int2 ed3 = sedge[i + 3];
        float x0 = bf2f(cur[(size_t)ed0.x * DD + lane]);
        float x1 = bf2f(cur[(size_t)ed1.x * DD + lane]);
        float x2 = bf2f(cur[(size_t)ed2.x * DD + lane]);
        float x3 = bf2f(cur[(size_t)ed3.x * DD + lane]);
        acc += __int_as_float(ed0.y) * x0;
        acc += __int_as_float(ed1.y) * x1;
        acc += __int_as_float(ed2.y) * x2;
        acc += __int_as_float(ed3.y) * x3;
    }
    for (; i < e; ++i) {
        int2 ed = sedge[i];
        acc += __int_as_float(ed.y) * bf2f(cur[(size_t)ed.x * DD + lane]);
    }
    size_t o = (size_t)row * DD + lane;
    if (nxt) nxt[o] = f2bf(acc);
    sum_[o] += acc;
}

// ---------- final gather + dot ----------
__global__ __launch_bounds__(256) void gamma_kernel(const int* __restrict__ users,
                                                    const int* __restrict__ items,
                                                    const float* __restrict__ sum_,
                                                    float* __restrict__ out) {
    int gid = blockIdx.x * 256 + threadIdx.x;
    int b = gid >> 6;
    int lane = gid & 63;
    if (b >= BBATCH) return;
    int u = users[b];
    int it = items[b];
    float pu = sum_[(size_t)u * DD + lane];
    float pi = sum_[(size_t)(NUM_USERS + it) * DD + lane];
    float p = pu * pi;
#pragma unroll
    for (int m = 32; m; m >>= 1) p += __shfl_xor(p, m);
    if (lane == 0) out[b] = p * 0.0625f;
}

extern "C" void kernel_launch(void* const* d_in, const int* in_sizes, int n_in,
                              void* d_out, int out_size, void* d_ws, size_t ws_size,
                              hipStream_t stream) {
    const int* users = (const int*)d_in[0];
    const int* items = (const int*)d_in[1];
    const int* adj = (const int*)d_in[2];
    const int* grows = (const int*)d_in[3];
    const int* gcols = (const int*)d_in[4];
    const float* gvals = (const float*)d_in[5];
    const float* sem = (const float*)d_in[6];
    const float* usem = (const float*)d_in[7];
    const float* emb_user = (const float*)d_in[8];
    const float* emb_item = (const float*)d_in[9];
    const float* W_sem = (const float*)d_in[10];
    const float* b_sem = (const float*)d_in[11];
    const float* W_usem = (const float*)d_in[12];
    const float* b_usem = (const float*)d_in[13];
    const float* W_att = (const float*)d_in[14];
    const float* a_att = (const float*)d_in[15];
    float* out = (float*)d_out;

    const size_t NE = (size_t)NTOT * DD;          // 5.76M
    const size_t IE = (size_t)NUM_ITEMS * DD;     // 1.92M
    char* p = (char*)d_ws;
    float* sum_ = (float*)p;        p += NE * 4;
    ushort_t* cur16 = (ushort_t*)p; p += NE * 2;
    ushort_t* nxt16 = (ushort_t*)p; p += NE * 2;
    float* M0 = (float*)p;          p += IE * 4;
    ushort_t* M0h = (ushort_t*)p;   p += IE * 2;
    int2* sedge = (int2*)p;         p += (size_t)NNZE * 8;
    ushort_t* WThiU = (ushort_t*)p; p += 65536 * 2;
    ushort_t* WTloU = (ushort_t*)p; p += 65536 * 2;
    ushort_t* WThiS = (ushort_t*)p; p += 65536 * 2;
    ushort_t* WTloS = (ushort_t*)p; p += 65536 * 2;
    float* s1 = (float*)p;          p += NUM_ITEMS * 4;
    float* s2 = (float*)p;          p += NUM_ITEMS * 4;
    float* wa1 = (float*)p;         p += SEMD * 4;
    float* wa2 = (float*)p;         p += SEMD * 4;
    int* cnt = (int*)p;             p += NTOT * 4;
    int* rowptr = (int*)p;          p += (NTOT + 4) * 4;
    int* cursor = (int*)p;          p += NTOT * 4;
    int* bsum = (int*)p;            p += 96 * 4;
    int* boff = (int*)p;            p += 96 * 4;
    int* bcursor = (int*)p;         p += NBKT * 4;

    wsplit<<<513, 256, 0, stream>>>(W_usem, W_sem, WThiU, WTloU, WThiS, WTloS,
                                    W_att, a_att, wa1, wa2);

    gemm_mfma<false><<<(NUM_USERS + 127) / 128, 256, 0, stream>>>(
        usem, WThiU, WTloU, b_usem, emb_user, sum_, cur16, NUM_USERS,
        nullptr, nullptr, nullptr, nullptr);
    gemm_mfma<true><<<(NUM_ITEMS + 127) / 128, 256, 0, stream>>>(
        sem, WThiS, WTloS, b_sem, emb_item, M0, M0h, NUM_ITEMS,
        wa1, wa2, s1, s2);

    att_kernel<<<(NUM_ITEMS * 64 + 255) / 256, 256, 0, stream>>>(adj, s1, s2, M0, M0h,
                                                                 cur16, sum_);

    hipMemsetAsync(cnt, 0, NTOT * sizeof(int), stream);
    hist_kernel<<<(NNZE + 255) / 256, 256, 0, stream>>>(grows, cnt);
    scan_blocksums<<<SCAN_NB, 256, 0, stream>>>(cnt, bsum);
    scan_bsums<<<1, 128, 0, stream>>>(bsum, boff, rowptr);
    scan_write<<<SCAN_NB, 256, 0, stream>>>(cnt, boff, rowptr, cursor, bcursor);
    binA<<<(NNZE + 4095) / 4096, 256, 0, stream>>>(grows, gcols, gvals, bcursor, sedge);
    binB<<<NBKT, 256, 0, stream>>>(rowptr, cursor, sedge);

    ushort_t* cur = cur16;
    ushort_t* nxt = nxt16;
    for (int l = 0; l < NLAYERS; ++l) {
        spmm16<<<(NTOT * 64 + 255) / 256, 256, 0, stream>>>(
            rowptr, sedge, cur, (l == NLAYERS - 1) ? nullptr : nxt, sum_);
        ushort_t* t = cur;
        cur = nxt;
        nxt = t;
    }
    gamma_kernel<<<(BBATCH * 64 + 255) / 256, 256, 0, stream>>>(users, items, sum_, out);
}